// Round 4
// baseline (1175.592 us; speedup 1.0000x reference)
//
#include <hip/hip_runtime.h>
#include <hip/hip_bf16.h>
#include <math.h>

#define NBATCH 2048
#define NAG 32
#define HIDD 256
#define INDIM 256
#define PIN 320
#define NACTN 20
#define NEGV -1e10f
#define MT 64                      // rows per block in K1/K3
#define NROWS (NBATCH*NAG)         // 65536

typedef __attribute__((ext_vector_type(8))) __bf16 bf16x8;
typedef __attribute__((ext_vector_type(4))) float f32x4;

// ---- bf16 weight cache layout in d_ws (element offsets) ----
#define WO_W1   0
#define WO_WIH  65536
#define WO_WHH  262144
#define WO_WQ   458752
#define WO_WK   475136
#define WO_WV   491520
#define WO_WG   507904
#define WO_WP1  508928
#define WO_WP2  590848
// ---- bf16 intermediates in d_ws (element offsets) ----
#define WSO_Q   1048576                  // [NROWS][64]
#define WSO_K   (WSO_Q + NROWS*64)
#define WSO_V   (WSO_K + NROWS*64)
#define WSO_G   (WSO_V + NROWS*64)       // [NROWS][4]
#define WSO_MSG (WSO_G + NROWS*4)        // [NROWS][64]

__device__ __forceinline__ unsigned short f2bf(float f) {
    union { float f; unsigned int i; } x; x.f = f;
    unsigned int r = x.i + 0x7fffu + ((x.i >> 16) & 1u);
    return (unsigned short)(r >> 16);
}
__device__ __forceinline__ float bf2f(unsigned short u) {
    union { unsigned int i; float f; } x; x.i = ((unsigned int)u) << 16; return x.f;
}
__device__ __forceinline__ float frcp(float x) { return __builtin_amdgcn_rcpf(x); }
__device__ __forceinline__ float sigm(float x) { return frcp(1.0f + __expf(-x)); }
__device__ __forceinline__ float tanh_fast(float x) {
    float e = __expf(2.0f * x);
    return 1.0f - 2.0f * frcp(e + 1.0f);
}

// swizzled addressing for 256-col bf16 buffers
__device__ __forceinline__ int swz(int row, int col) {
    return row*256 + ((((col >> 3)) ^ (row & 7)) << 3) + (col & 7);
}
__device__ __forceinline__ int swzf(int row, int frag) {   // 8-elem fragment base
    return row*256 + ((frag ^ (row & 7)) << 3);
}
// swizzled addressing for 64-col bf16 msg buffer
__device__ __forceinline__ int swzf64(int row, int frag) {
    return row*64 + ((frag ^ (row & 7)) << 3);
}

__device__ __forceinline__ bf16x8 ldfrag(const unsigned short* p) {
    return *(const bf16x8*)(const void*)p;
}
union ZU { uint4 u; bf16x8 v; };
__device__ __forceinline__ bf16x8 zfrag() {
    ZU x; x.u = make_uint4(0u, 0u, 0u, 0u); return x.v;
}
#define MFMA(a,b,c) __builtin_amdgcn_mfma_f32_16x16x32_bf16(a,b,c,0,0,0)

// ---- pre-pass: convert fp32 weight matrices to bf16 in d_ws ----
__global__ void __launch_bounds__(256)
convert_weights(const float* __restrict__ W1,  const float* __restrict__ Wih,
                const float* __restrict__ Whh, const float* __restrict__ Wq,
                const float* __restrict__ Wk,  const float* __restrict__ Wv,
                const float* __restrict__ Wg,  const float* __restrict__ Wp1,
                const float* __restrict__ Wp2, unsigned short* __restrict__ dst)
{
    int b = (int)blockIdx.x;
    const float* src; int base;
    if      (b <  64) { src = W1;  base = WO_W1;              }
    else if (b < 256) { src = Wih; base = WO_WIH; b -=  64;   }
    else if (b < 448) { src = Whh; base = WO_WHH; b -= 256;   }
    else if (b < 464) { src = Wq;  base = WO_WQ;  b -= 448;   }
    else if (b < 480) { src = Wk;  base = WO_WK;  b -= 464;   }
    else if (b < 496) { src = Wv;  base = WO_WV;  b -= 480;   }
    else if (b < 497) { src = Wg;  base = WO_WG;  b -= 496;   }
    else if (b < 577) { src = Wp1; base = WO_WP1; b -= 497;   }
    else              { src = Wp2; base = WO_WP2; b -= 577;   }
    const int idx = b * 1024 + (int)threadIdx.x * 4;
    float4 v = *(const float4*)(const void*)(src + idx);
    ushort4 u;
    u.x = f2bf(v.x); u.y = f2bf(v.y); u.z = f2bf(v.z); u.w = f2bf(v.w);
    *(ushort4*)(void*)(dst + base + idx) = u;
}

// one GRU gate accumulation pass: ia += x @ Wg^T, ha += h_old @ Vg^T
__device__ __forceinline__ void gru_pass(
    const unsigned short* __restrict__ lA, const unsigned short* __restrict__ lB,
    const unsigned short* __restrict__ wi, const unsigned short* __restrict__ wh,
    int l15, int quad, f32x4* ia, f32x4* ha)
{
    #pragma unroll
    for (int m = 0; m < 4; ++m) {
        ia[m] = (f32x4){0.f,0.f,0.f,0.f};
        ha[m] = (f32x4){0.f,0.f,0.f,0.f};
    }
    #pragma unroll
    for (int kt = 0; kt < 8; ++kt) {
        const int frag = kt*4 + quad;
        const int k0 = frag*8;
        bf16x8 bw = ldfrag(wi + k0);
        bf16x8 cw = ldfrag(wh + k0);
        #pragma unroll
        for (int m = 0; m < 4; ++m) {
            ia[m] = MFMA(ldfrag(lA + swzf(m*16 + l15, frag)), bw, ia[m]);
            ha[m] = MFMA(ldfrag(lB + swzf(m*16 + l15, frag)), cw, ha[m]);
        }
    }
}

// =====================================================================
// K1: 64 rows/block, 512 threads (8 waves), 2 x 32KB LDS, 2 blocks/CU
//     = 16 waves/CU. GRU gate-split (r/z/n) keeps regs under the
//     (512,4) budget (~128/wave) -> no scratch spills.
// =====================================================================
__global__ void __launch_bounds__(512, 4)
k1_gru_qkvg(const float* __restrict__ gIn, const float* __restrict__ gH,
            const unsigned short* __restrict__ wsW,
            const float* __restrict__ B1,
            const float* __restrict__ Bih, const float* __restrict__ Bhh,
            const float* __restrict__ Bq,  const float* __restrict__ Bk,
            const float* __restrict__ Bv,  const float* __restrict__ Bg,
            float* __restrict__ outH,
            unsigned short* __restrict__ wsQ, unsigned short* __restrict__ wsK,
            unsigned short* __restrict__ wsV, unsigned short* __restrict__ wsG)
{
    __shared__ __align__(16) unsigned short lA[MT*256];   // IN -> x -> h_new
    __shared__ __align__(16) unsigned short lB[MT*256];   // h_old

    const unsigned short* W1  = wsW + WO_W1;
    const unsigned short* Wih = wsW + WO_WIH;
    const unsigned short* Whh = wsW + WO_WHH;
    const unsigned short* Wq  = wsW + WO_WQ;
    const unsigned short* Wk  = wsW + WO_WK;
    const unsigned short* Wv  = wsW + WO_WV;
    const unsigned short* Wg  = wsW + WO_WG;

    const int tid  = (int)threadIdx.x;
    const int lane = tid & 63;
    const int wv   = tid >> 6;          // 0..7
    const int l15  = lane & 15;
    const int quad = lane >> 4;
    const long rowBase = (long)blockIdx.x * MT;

    // ---- P0: stage IN -> lA, h_old -> lB (fp32 -> bf16, swizzled) ----
    #pragma unroll
    for (int i = 0; i < 8; ++i) {
        const int job  = i*512 + tid;        // 4096 = 2 bufs x 64 rows x 32 frags
        const int frag = job & 31;
        const int row  = (job >> 5) & 63;
        const int buf  = job >> 11;
        const float* src = (buf ? gH : gIn) + (rowBase + row)*256 + frag*8;
        float4 v0 = *(const float4*)(const void*)(src);
        float4 v1 = *(const float4*)(const void*)(src + 4);
        uint4 pk;
        pk.x = ((unsigned int)f2bf(v0.y) << 16) | f2bf(v0.x);
        pk.y = ((unsigned int)f2bf(v0.w) << 16) | f2bf(v0.z);
        pk.z = ((unsigned int)f2bf(v1.y) << 16) | f2bf(v1.x);
        pk.w = ((unsigned int)f2bf(v1.w) << 16) | f2bf(v1.z);
        unsigned short* dst = buf ? lB : lA;
        *(uint4*)(void*)(dst + swzf(row, frag)) = pk;
    }
    __syncthreads();

    // ---- P1: x = relu(IN @ W1^T + b1) -> regs, then overlay onto lA ----
    f32x4 xa[2][4];
    #pragma unroll
    for (int i4 = 0; i4 < 2; ++i4) {
        const int nt = i4*8 + wv;
        const int n  = nt*16 + l15;
        f32x4 a0 = {0.f,0.f,0.f,0.f}, a1 = {0.f,0.f,0.f,0.f};
        f32x4 a2 = {0.f,0.f,0.f,0.f}, a3 = {0.f,0.f,0.f,0.f};
        #pragma unroll
        for (int kt = 0; kt < 8; ++kt) {
            const int frag = kt*4 + quad;
            bf16x8 bw = ldfrag(W1 + n*INDIM + frag*8);
            a0 = MFMA(ldfrag(lA + swzf(     l15, frag)), bw, a0);
            a1 = MFMA(ldfrag(lA + swzf(16 + l15, frag)), bw, a1);
            a2 = MFMA(ldfrag(lA + swzf(32 + l15, frag)), bw, a2);
            a3 = MFMA(ldfrag(lA + swzf(48 + l15, frag)), bw, a3);
        }
        const float b = B1[n];
        #pragma unroll
        for (int r = 0; r < 4; ++r) {
            a0[r] = fmaxf(a0[r] + b, 0.f); a1[r] = fmaxf(a1[r] + b, 0.f);
            a2[r] = fmaxf(a2[r] + b, 0.f); a3[r] = fmaxf(a3[r] + b, 0.f);
        }
        xa[i4][0] = a0; xa[i4][1] = a1; xa[i4][2] = a2; xa[i4][3] = a3;
    }
    __syncthreads();              // all IN reads complete
    #pragma unroll
    for (int i4 = 0; i4 < 2; ++i4) {
        const int nt = i4*8 + wv;
        #pragma unroll
        for (int m = 0; m < 4; ++m) {
            #pragma unroll
            for (int r = 0; r < 4; ++r)
                lA[swz(m*16 + quad*4 + r, nt*16 + l15)] = f2bf(xa[i4][m][r]);
        }
    }
    __syncthreads();

    // ---- P2: GRU, gate-split into 3 low-register passes ----
    for (int jt = wv; jt < 16; jt += 8) {
        const int n = jt*16 + l15;
        float rr[16], zz[16];
        {   // reset gate
            f32x4 ia[4], ha[4];
            gru_pass(lA, lB, Wih + (size_t)n*HIDD, Whh + (size_t)n*HIDD,
                     l15, quad, ia, ha);
            const float bi = Bih[n], bh = Bhh[n];
            #pragma unroll
            for (int m = 0; m < 4; ++m)
                #pragma unroll
                for (int r = 0; r < 4; ++r)
                    rr[m*4+r] = sigm(ia[m][r] + bi + ha[m][r] + bh);
        }
        {   // update gate
            f32x4 ia[4], ha[4];
            gru_pass(lA, lB, Wih + (size_t)(n+256)*HIDD, Whh + (size_t)(n+256)*HIDD,
                     l15, quad, ia, ha);
            const float bi = Bih[n+256], bh = Bhh[n+256];
            #pragma unroll
            for (int m = 0; m < 4; ++m)
                #pragma unroll
                for (int r = 0; r < 4; ++r)
                    zz[m*4+r] = sigm(ia[m][r] + bi + ha[m][r] + bh);
        }
        {   // candidate + blend
            f32x4 ia[4], ha[4];
            gru_pass(lA, lB, Wih + (size_t)(n+512)*HIDD, Whh + (size_t)(n+512)*HIDD,
                     l15, quad, ia, ha);
            const float bi = Bih[n+512], bh = Bhh[n+512];
            #pragma unroll
            for (int m = 0; m < 4; ++m) {
                #pragma unroll
                for (int r = 0; r < 4; ++r) {
                    const int row = m*16 + quad*4 + r;
                    const float hprev = bf2f(lB[swz(row, n)]);
                    const float nn = tanh_fast(ia[m][r] + bi + rr[m*4+r]*(ha[m][r] + bh));
                    outH[(rowBase + row)*HIDD + n] =
                        (1.0f - zz[m*4+r])*nn + zz[m*4+r]*hprev;
                }
            }
        }
    }
    __syncthreads();              // all lA(x)/lB reads complete

    // ---- P3: restage h_new (fp32, L2-hot) -> lA as bf16 ----
    #pragma unroll
    for (int i = 0; i < 4; ++i) {
        const int job  = i*512 + tid;        // 2048 = 64 rows x 32 frags
        const int frag = job & 31;
        const int row  = job >> 5;
        const float* src = outH + (rowBase + row)*256 + frag*8;
        float4 v0 = *(const float4*)(const void*)(src);
        float4 v1 = *(const float4*)(const void*)(src + 4);
        uint4 pk;
        pk.x = ((unsigned int)f2bf(v0.y) << 16) | f2bf(v0.x);
        pk.y = ((unsigned int)f2bf(v0.w) << 16) | f2bf(v0.z);
        pk.z = ((unsigned int)f2bf(v1.y) << 16) | f2bf(v1.x);
        pk.w = ((unsigned int)f2bf(v1.w) << 16) | f2bf(v1.z);
        *(uint4*)(void*)(lA + swzf(row, frag)) = pk;
    }
    __syncthreads();

    // ---- P4: q,k,v,g -> global bf16 ----
    for (int job = wv; job < 13; job += 8) {
        const unsigned short* W; const float* Bi; unsigned short* dst; int nb;
        if      (job < 4)  { W = Wq; Bi = Bq; dst = wsQ; nb = job;     }
        else if (job < 8)  { W = Wk; Bi = Bk; dst = wsK; nb = job - 4; }
        else if (job < 12) { W = Wv; Bi = Bv; dst = wsV; nb = job - 8; }
        else               { W = Wg; Bi = Bg; dst = wsG; nb = 0;       }
        const bool isg   = (job == 12);
        const bool valid = !isg || (l15 < 4);
        const int n = nb*16 + l15;
        f32x4 ac[4];
        #pragma unroll
        for (int m = 0; m < 4; ++m) ac[m] = (f32x4){0.f,0.f,0.f,0.f};
        #pragma unroll
        for (int kt = 0; kt < 8; ++kt) {
            const int frag = kt*4 + quad;
            bf16x8 bw = valid ? ldfrag(W + n*HIDD + frag*8) : zfrag();
            #pragma unroll
            for (int m = 0; m < 4; ++m)
                ac[m] = MFMA(ldfrag(lA + swzf(m*16 + l15, frag)), bw, ac[m]);
        }
        if (valid) {
            const float b = Bi[n];
            #pragma unroll
            for (int m = 0; m < 4; ++m) {
                #pragma unroll
                for (int r = 0; r < 4; ++r) {
                    const int row = m*16 + quad*4 + r;
                    const float v = ac[m][r] + b;
                    if (isg) dst[(rowBase + row)*4  + l15]          = f2bf(v);
                    else     dst[(rowBase + row)*64 + nb*16 + l15]  = f2bf(v);
                }
            }
        }
    }
}

// =====================================================================
// K2: sparse attention. 2 batches/block, 1 (b,h,qi) job per thread.
// =====================================================================
#define QS 68   // padded LDS row stride (2-way bank aliasing only)
__global__ void __launch_bounds__(256, 4)
k2_attn(const unsigned short* __restrict__ wsQ, const unsigned short* __restrict__ wsK,
        const unsigned short* __restrict__ wsV, const unsigned short* __restrict__ wsG,
        unsigned short* __restrict__ wsM)
{
    __shared__ unsigned short sQ[2][32*QS];
    __shared__ unsigned short sK[2][32*QS];
    __shared__ unsigned short sV[2][32*QS];
    __shared__ unsigned short sG[2][32*4];

    const int tid = (int)threadIdx.x;
    const long b0 = (long)blockIdx.x * 2;

    #pragma unroll
    for (int i = 0; i < 12; ++i) {
        const int j  = i*256 + tid;
        const int b  = (j >= 1536) ? 1 : 0;
        const int jj = b ? (j - 1536) : j;
        const int mat = jj >> 9;
        const int e   = jj & 511;
        const int row = e >> 4, c4 = e & 15;
        const unsigned short* srcm = (mat == 0) ? wsQ : (mat == 1) ? wsK : wsV;
        unsigned short* dstm = (mat == 0) ? sQ[b] : (mat == 1) ? sK[b] : sV[b];
        *(ushort4*)(void*)(dstm + row*QS + c4*4) =
            *(const ushort4*)(const void*)(srcm + ((b0 + b)*32 + row)*64 + c4*4);
    }
    if (tid < 64) {
        const int b = tid >> 5, row = tid & 31;
        *(ushort4*)(void*)(sG[b] + row*4) =
            *(const ushort4*)(const void*)(wsG + ((b0 + b)*32 + row)*4);
    }
    __syncthreads();

    const int b  = tid >> 7;
    const int h  = (tid >> 5) & 3;
    const int qi = tid & 31;
    const unsigned short* q_ = sQ[b];
    const unsigned short* k_ = sK[b];
    const unsigned short* v_ = sV[b];

    float qv[16];
    #pragma unroll
    for (int c = 0; c < 16; ++c) qv[c] = bf2f(q_[qi*QS + h*16 + c]);
    float s0[32];
    #pragma unroll
    for (int ki = 0; ki < 32; ++ki) {
        float acc = 0.0f;
        #pragma unroll
        for (int c = 0; c < 16; ++c) acc += qv[c] * bf2f(k_[ki*QS + h*16 + c]);
        acc *= 0.25f;                        // 1/sqrt(16)
        s0[ki] = (ki == qi) ? NEGV : acc;    // diagonal mask
    }
    // top-8, lowest index wins ties (matches lax.top_k)
    unsigned int mask = 0u;
    float m1 = 0.0f;
    for (int t = 0; t < 8; ++t) {
        float best = -3.0e38f; int bidx = 0;
        #pragma unroll
        for (int i = 0; i < 32; ++i) {
            bool better = (((mask >> i) & 1u) == 0u) && (s0[i] > best);
            best = better ? s0[i] : best;
            bidx = better ? i : bidx;
        }
        mask |= (1u << bidx);
        if (t == 0) m1 = best;
    }
    float sum = 0.0f;
    #pragma unroll
    for (int i = 0; i < 32; ++i) {
        const float e = ((mask >> i) & 1u) ? __expf(s0[i] - m1) : 0.0f;
        s0[i] = e;                            // cache exp for PV pass
        sum += e;
    }
    const float inv = frcp(sum);
    const float gate = sigm(bf2f(sG[b][qi*4 + h]));
    float msg[16];
    #pragma unroll
    for (int c = 0; c < 16; ++c) msg[c] = 0.0f;
    #pragma unroll
    for (int ki = 0; ki < 32; ++ki) {
        const float al = s0[ki] * inv;
        #pragma unroll
        for (int c = 0; c < 16; ++c) msg[c] += al * bf2f(v_[ki*QS + h*16 + c]);
    }
    unsigned short mb[16];
    #pragma unroll
    for (int c = 0; c < 16; ++c) mb[c] = f2bf(msg[c] * gate);
    unsigned short* dst = wsM + ((b0 + b)*32 + qi)*64 + h*16;
    #pragma unroll
    for (int c4 = 0; c4 < 4; ++c4) {
        ushort4 u;
        u.x = mb[c4*4]; u.y = mb[c4*4+1]; u.z = mb[c4*4+2]; u.w = mb[c4*4+3];
        *(ushort4*)(void*)(dst + c4*4) = u;
    }
}

// =====================================================================
// K3: policy head. 64 rows/block, 512 threads. p1x goes to its own LDS
//     buffer lP (no cross-barrier register carry) -> ~60 regs/thread,
//     2 blocks/CU (72KB LDS) = 16 waves/CU.
// =====================================================================
__global__ void __launch_bounds__(512, 4)
k3_policy(const float* __restrict__ gHnew, const unsigned short* __restrict__ wsW,
          const unsigned short* __restrict__ wsM,
          const float* __restrict__ Bp1, const float* __restrict__ Bp2,
          float* __restrict__ outL)
{
    __shared__ __align__(16) unsigned short lH[MT*256];   // h (bf16 swz)
    __shared__ __align__(16) unsigned short lM[MT*64];    // msg
    __shared__ __align__(16) unsigned short lP[MT*256];   // p1x

    const unsigned short* Wp1 = wsW + WO_WP1;
    const unsigned short* Wp2 = wsW + WO_WP2;

    const int tid  = (int)threadIdx.x;
    const int lane = tid & 63;
    const int wv   = tid >> 6;          // 0..7
    const int l15  = lane & 15;
    const int quad = lane >> 4;
    const long rowBase = (long)blockIdx.x * MT;

    // stage h (fp32 -> bf16, swizzled)
    #pragma unroll
    for (int i = 0; i < 4; ++i) {
        const int job  = i*512 + tid;        // 2048 = 64 rows x 32 frags
        const int frag = job & 31;
        const int row  = job >> 5;
        const float* src = gHnew + (rowBase + row)*256 + frag*8;
        float4 v0 = *(const float4*)(const void*)(src);
        float4 v1 = *(const float4*)(const void*)(src + 4);
        uint4 pk;
        pk.x = ((unsigned int)f2bf(v0.y) << 16) | f2bf(v0.x);
        pk.y = ((unsigned int)f2bf(v0.w) << 16) | f2bf(v0.z);
        pk.z = ((unsigned int)f2bf(v1.y) << 16) | f2bf(v1.x);
        pk.w = ((unsigned int)f2bf(v1.w) << 16) | f2bf(v1.z);
        *(uint4*)(void*)(lH + swzf(row, frag)) = pk;
    }
    // stage msg (bf16, swizzled 64-col): 512 jobs
    {
        const int frag = tid & 7;
        const int row  = tid >> 3;
        *(uint4*)(void*)(lM + swzf64(row, frag)) =
            *(const uint4*)(const void*)(wsM + (rowBase + row)*64 + frag*8);
    }
    __syncthreads();

    // p1x = relu([h | msg] @ Wp1^T + b) -> straight to lP
    #pragma unroll
    for (int i4 = 0; i4 < 2; ++i4) {
        const int nt = i4*8 + wv;
        const int n  = nt*16 + l15;
        f32x4 a0 = {0.f,0.f,0.f,0.f}, a1 = {0.f,0.f,0.f,0.f};
        f32x4 a2 = {0.f,0.f,0.f,0.f}, a3 = {0.f,0.f,0.f,0.f};
        #pragma unroll
        for (int kt = 0; kt < 10; ++kt) {
            bf16x8 bw = ldfrag(Wp1 + n*PIN + kt*32 + quad*8);
            bf16x8 f0, f1, f2, f3;
            if (kt < 8) {
                const int frag = kt*4 + quad;
                f0 = ldfrag(lH + swzf(     l15, frag));
                f1 = ldfrag(lH + swzf(16 + l15, frag));
                f2 = ldfrag(lH + swzf(32 + l15, frag));
                f3 = ldfrag(lH + swzf(48 + l15, frag));
            } else {
                const int frag = (kt - 8)*4 + quad;
                f0 = ldfrag(lM + swzf64(     l15, frag));
                f1 = ldfrag(lM + swzf64(16 + l15, frag));
                f2 = ldfrag(lM + swzf64(32 + l15, frag));
                f3 = ldfrag(lM + swzf64(48 + l15, frag));
            }
            a0 = MFMA(f0, bw, a0); a1 = MFMA(f1, bw, a1);
            a2 = MFMA(f2, bw, a2); a3 = MFMA(f3, bw, a3);
        }
        const float b = Bp1[n];
        #pragma unroll
        for (int r = 0; r < 4; ++r) {
            lP[swz(     quad*4 + r, n)] = f2bf(fmaxf(a0[r] + b, 0.f));
            lP[swz(16 + quad*4 + r, n)] = f2bf(fmaxf(a1[r] + b, 0.f));
            lP[swz(32 + quad*4 + r, n)] = f2bf(fmaxf(a2[r] + b, 0.f));
            lP[swz(48 + quad*4 + r, n)] = f2bf(fmaxf(a3[r] + b, 0.f));
        }
    }
    __syncthreads();

    // logits = p1x @ Wp2^T + b : 8 jobs, one per wave
    {
        const int ntile = wv >> 2, m = wv & 3;
        const int n = ntile*16 + l15;
        const bool valid = (n < NACTN);
        f32x4 ac = {0.f,0.f,0.f,0.f};
        #pragma unroll
        for (int kt = 0; kt < 8; ++kt) {
            const int frag = kt*4 + quad;
            bf16x8 bw = valid ? ldfrag(Wp2 + n*HIDD + frag*8) : zfrag();
            ac = MFMA(ldfrag(lP + swzf(m*16 + l15, frag)), bw, ac);
        }
        if (valid) {
            const float b = Bp2[n];
            #pragma unroll
            for (int r = 0; r < 4; ++r)
                outL[(rowBase + m*16 + quad*4 + r)*NACTN + n] = ac[r] + b;
        }
    }
}

extern "C" void kernel_launch(void* const* d_in, const int* in_sizes, int n_in,
                              void* d_out, int out_size, void* d_ws, size_t ws_size,
                              hipStream_t stream) {
    (void)in_sizes; (void)n_in; (void)ws_size; (void)out_size;
    const float* gIn = (const float*)d_in[0];
    const float* gH  = (const float*)d_in[1];
    const float* W1  = (const float*)d_in[2];
    const float* B1  = (const float*)d_in[3];
    const float* Wih = (const float*)d_in[4];
    const float* Whh = (const float*)d_in[5];
    const float* Bih = (const float*)d_in[6];
    const float* Bhh = (const float*)d_in[7];
    const float* Wq  = (const float*)d_in[8];
    const float* Bq  = (const float*)d_in[9];
    const float* Wk  = (const float*)d_in[10];
    const float* Bk  = (const float*)d_in[11];
    const float* Wv  = (const float*)d_in[12];
    const float* Bv  = (const float*)d_in[13];
    const float* Wg  = (const float*)d_in[14];
    const float* Bg  = (const float*)d_in[15];
    const float* Wp1 = (const float*)d_in[16];
    const float* Bp1 = (const float*)d_in[17];
    const float* Wp2 = (const float*)d_in[18];
    const float* Bp2 = (const float*)d_in[19];
    float* outL = (float*)d_out;
    float* outH = outL + (size_t)NBATCH * NAG * NACTN;
    unsigned short* wsW = (unsigned short*)d_ws;

    hipLaunchKernelGGL(convert_weights, dim3(582), dim3(256), 0, stream,
        W1, Wih, Whh, Wq, Wk, Wv, Wg, Wp1, Wp2, wsW);
    hipLaunchKernelGGL(k1_gru_qkvg, dim3(NROWS/MT), dim3(512), 0, stream,
        gIn, gH, wsW, B1, Bih, Bhh, Bq, Bk, Bv, Bg,
        outH, wsW + WSO_Q, wsW + WSO_K, wsW + WSO_V, wsW + WSO_G);
    hipLaunchKernelGGL(k2_attn, dim3(NBATCH/2), dim3(256), 0, stream,
        wsW + WSO_Q, wsW + WSO_K, wsW + WSO_V, wsW + WSO_G, wsW + WSO_MSG);
    hipLaunchKernelGGL(k3_policy, dim3(NROWS/MT), dim3(512), 0, stream,
        outH, wsW, wsW + WSO_MSG, Bp1, Bp2, outL);
}

// Round 5
// 398.302 us; speedup vs baseline: 2.9515x; 2.9515x over previous
//
#include <hip/hip_runtime.h>
#include <hip/hip_bf16.h>
#include <math.h>

#define NBATCH 2048
#define NAG 32
#define HIDD 256
#define INDIM 256
#define PIN 320
#define NACTN 20
#define NEGV -1e10f
#define MT 64                      // rows per block in K1/K23
#define NROWS (NBATCH*NAG)         // 65536

typedef __attribute__((ext_vector_type(8))) __bf16 bf16x8;
typedef __attribute__((ext_vector_type(4))) float f32x4;

// ---- bf16 weight cache layout in d_ws (element offsets) ----
#define WO_W1   0
#define WO_WIH  65536
#define WO_WHH  262144
#define WO_WQ   458752
#define WO_WK   475136
#define WO_WV   491520
#define WO_WG   507904
#define WO_WP1  508928
#define WO_WP2  590848
// ---- bf16 intermediates in d_ws (element offsets) ----
#define WSO_Q   1048576                  // [NROWS][64]
#define WSO_K   (WSO_Q + NROWS*64)
#define WSO_V   (WSO_K + NROWS*64)
#define WSO_G   (WSO_V + NROWS*64)       // [NROWS][4]

__device__ __forceinline__ unsigned short f2bf(float f) {
    union { float f; unsigned int i; } x; x.f = f;
    unsigned int r = x.i + 0x7fffu + ((x.i >> 16) & 1u);
    return (unsigned short)(r >> 16);
}
__device__ __forceinline__ float bf2f(unsigned short u) {
    union { unsigned int i; float f; } x; x.i = ((unsigned int)u) << 16; return x.f;
}
__device__ __forceinline__ float frcp(float x) { return __builtin_amdgcn_rcpf(x); }
__device__ __forceinline__ float sigm(float x) { return frcp(1.0f + __expf(-x)); }
__device__ __forceinline__ float tanh_fast(float x) {
    float e = __expf(2.0f * x);
    return 1.0f - 2.0f * frcp(e + 1.0f);
}

// swizzled addressing for 256-col bf16 buffers
__device__ __forceinline__ int swz(int row, int col) {
    return row*256 + ((((col >> 3)) ^ (row & 7)) << 3) + (col & 7);
}
__device__ __forceinline__ int swzf(int row, int frag) {   // 8-elem fragment base
    return row*256 + ((frag ^ (row & 7)) << 3);
}
// swizzled addressing for 64-col bf16 msg buffer
__device__ __forceinline__ int swz64(int row, int col) {
    return row*64 + ((((col >> 3)) ^ (row & 7)) << 3) + (col & 7);
}
__device__ __forceinline__ int swzf64(int row, int frag) {
    return row*64 + ((frag ^ (row & 7)) << 3);
}

__device__ __forceinline__ bf16x8 ldfrag(const unsigned short* p) {
    return *(const bf16x8*)(const void*)p;
}
union ZU { uint4 u; bf16x8 v; };
__device__ __forceinline__ bf16x8 zfrag() {
    ZU x; x.u = make_uint4(0u, 0u, 0u, 0u); return x.v;
}
#define MFMA(a,b,c) __builtin_amdgcn_mfma_f32_16x16x32_bf16(a,b,c,0,0,0)

// ---- pre-pass: convert fp32 weight matrices to bf16 in d_ws ----
__global__ void __launch_bounds__(256)
convert_weights(const float* __restrict__ W1,  const float* __restrict__ Wih,
                const float* __restrict__ Whh, const float* __restrict__ Wq,
                const float* __restrict__ Wk,  const float* __restrict__ Wv,
                const float* __restrict__ Wg,  const float* __restrict__ Wp1,
                const float* __restrict__ Wp2, unsigned short* __restrict__ dst)
{
    int b = (int)blockIdx.x;
    const float* src; int base;
    if      (b <  64) { src = W1;  base = WO_W1;              }
    else if (b < 256) { src = Wih; base = WO_WIH; b -=  64;   }
    else if (b < 448) { src = Whh; base = WO_WHH; b -= 256;   }
    else if (b < 464) { src = Wq;  base = WO_WQ;  b -= 448;   }
    else if (b < 480) { src = Wk;  base = WO_WK;  b -= 464;   }
    else if (b < 496) { src = Wv;  base = WO_WV;  b -= 480;   }
    else if (b < 497) { src = Wg;  base = WO_WG;  b -= 496;   }
    else if (b < 577) { src = Wp1; base = WO_WP1; b -= 497;   }
    else              { src = Wp2; base = WO_WP2; b -= 577;   }
    const int idx = b * 1024 + (int)threadIdx.x * 4;
    float4 v = *(const float4*)(const void*)(src + idx);
    ushort4 u;
    u.x = f2bf(v.x); u.y = f2bf(v.y); u.z = f2bf(v.z); u.w = f2bf(v.w);
    *(ushort4*)(void*)(dst + base + idx) = u;
}

// =====================================================================
// K1: 64 rows/block, 256 threads, 2 x 32KB LDS, (256,2) -> VGPR 128,
// no spills (R1-proven). fc1 -> GRU -> q,k,v,g. Fast transcendentals.
// =====================================================================
__global__ void __launch_bounds__(256, 2)
k1_gru_qkvg(const float* __restrict__ gIn, const float* __restrict__ gH,
            const unsigned short* __restrict__ wsW,
            const float* __restrict__ B1,
            const float* __restrict__ Bih, const float* __restrict__ Bhh,
            const float* __restrict__ Bq,  const float* __restrict__ Bk,
            const float* __restrict__ Bv,  const float* __restrict__ Bg,
            float* __restrict__ outH,
            unsigned short* __restrict__ wsQ, unsigned short* __restrict__ wsK,
            unsigned short* __restrict__ wsV, unsigned short* __restrict__ wsG)
{
    __shared__ __align__(16) unsigned short lA[MT*256];   // IN -> x -> h_new
    __shared__ __align__(16) unsigned short lB[MT*256];   // h_old

    const unsigned short* W1  = wsW + WO_W1;
    const unsigned short* Wih = wsW + WO_WIH;
    const unsigned short* Whh = wsW + WO_WHH;
    const unsigned short* Wq  = wsW + WO_WQ;
    const unsigned short* Wk  = wsW + WO_WK;
    const unsigned short* Wv  = wsW + WO_WV;
    const unsigned short* Wg  = wsW + WO_WG;

    const int tid  = (int)threadIdx.x;
    const int lane = tid & 63;
    const int wv   = tid >> 6;
    const int l15  = lane & 15;
    const int quad = lane >> 4;
    const long rowBase = (long)blockIdx.x * MT;

    // ---- P0: stage IN -> lA, h_old -> lB (fp32 -> bf16, swizzled) ----
    #pragma unroll
    for (int i = 0; i < 16; ++i) {
        const int job  = i*256 + tid;        // 4096 = 2 bufs x 64 rows x 32 frags
        const int frag = job & 31;
        const int row  = (job >> 5) & 63;
        const int buf  = job >> 11;
        const float* src = (buf ? gH : gIn) + (rowBase + row)*256 + frag*8;
        float4 v0 = *(const float4*)(const void*)(src);
        float4 v1 = *(const float4*)(const void*)(src + 4);
        uint4 pk;
        pk.x = ((unsigned int)f2bf(v0.y) << 16) | f2bf(v0.x);
        pk.y = ((unsigned int)f2bf(v0.w) << 16) | f2bf(v0.z);
        pk.z = ((unsigned int)f2bf(v1.y) << 16) | f2bf(v1.x);
        pk.w = ((unsigned int)f2bf(v1.w) << 16) | f2bf(v1.z);
        unsigned short* dst = buf ? lB : lA;
        *(uint4*)(void*)(dst + swzf(row, frag)) = pk;
    }
    __syncthreads();

    // ---- P1: x = relu(IN @ W1^T + b1) -> regs, then overlay onto lA ----
    f32x4 xa[4][4];
    #pragma unroll
    for (int i4 = 0; i4 < 4; ++i4) {
        const int nt = i4*4 + wv;
        const int n  = nt*16 + l15;
        f32x4 a0 = {0.f,0.f,0.f,0.f}, a1 = {0.f,0.f,0.f,0.f};
        f32x4 a2 = {0.f,0.f,0.f,0.f}, a3 = {0.f,0.f,0.f,0.f};
        #pragma unroll
        for (int kt = 0; kt < 8; ++kt) {
            const int frag = kt*4 + quad;
            bf16x8 bw = ldfrag(W1 + n*INDIM + frag*8);
            a0 = MFMA(ldfrag(lA + swzf(     l15, frag)), bw, a0);
            a1 = MFMA(ldfrag(lA + swzf(16 + l15, frag)), bw, a1);
            a2 = MFMA(ldfrag(lA + swzf(32 + l15, frag)), bw, a2);
            a3 = MFMA(ldfrag(lA + swzf(48 + l15, frag)), bw, a3);
        }
        const float b = B1[n];
        #pragma unroll
        for (int r = 0; r < 4; ++r) {
            a0[r] = fmaxf(a0[r] + b, 0.f); a1[r] = fmaxf(a1[r] + b, 0.f);
            a2[r] = fmaxf(a2[r] + b, 0.f); a3[r] = fmaxf(a3[r] + b, 0.f);
        }
        xa[i4][0] = a0; xa[i4][1] = a1; xa[i4][2] = a2; xa[i4][3] = a3;
    }
    __syncthreads();              // all IN reads complete
    #pragma unroll
    for (int i4 = 0; i4 < 4; ++i4) {
        const int nt = i4*4 + wv;
        #pragma unroll
        for (int m = 0; m < 4; ++m) {
            #pragma unroll
            for (int r = 0; r < 4; ++r)
                lA[swz(m*16 + quad*4 + r, nt*16 + l15)] = f2bf(xa[i4][m][r]);
        }
    }
    __syncthreads();

    // ---- P2: GRU -> h_new (fp32 to outH) ----
    for (int jt = wv; jt < 16; jt += 4) {
        const int n = jt*16 + l15;
        f32x4 ir[4], iz[4], in_[4], hr[4], hz[4], hn[4];
        #pragma unroll
        for (int m = 0; m < 4; ++m) {
            ir[m] = (f32x4){0.f,0.f,0.f,0.f}; iz[m] = (f32x4){0.f,0.f,0.f,0.f};
            in_[m]= (f32x4){0.f,0.f,0.f,0.f}; hr[m] = (f32x4){0.f,0.f,0.f,0.f};
            hz[m] = (f32x4){0.f,0.f,0.f,0.f}; hn[m] = (f32x4){0.f,0.f,0.f,0.f};
        }
        #pragma unroll 2
        for (int kt = 0; kt < 8; ++kt) {
            const int frag = kt*4 + quad;
            const int k0 = frag*8;
            bf16x8 ax[4], ah[4];
            #pragma unroll
            for (int m = 0; m < 4; ++m) {
                ax[m] = ldfrag(lA + swzf(m*16 + l15, frag));
                ah[m] = ldfrag(lB + swzf(m*16 + l15, frag));
            }
            bf16x8 br = ldfrag(Wih + (n      )*HIDD + k0);
            bf16x8 bz = ldfrag(Wih + (n + 256)*HIDD + k0);
            bf16x8 bn = ldfrag(Wih + (n + 512)*HIDD + k0);
            bf16x8 cr = ldfrag(Whh + (n      )*HIDD + k0);
            bf16x8 cz = ldfrag(Whh + (n + 256)*HIDD + k0);
            bf16x8 cn = ldfrag(Whh + (n + 512)*HIDD + k0);
            #pragma unroll
            for (int m = 0; m < 4; ++m) {
                ir[m] = MFMA(ax[m], br, ir[m]);
                iz[m] = MFMA(ax[m], bz, iz[m]);
                in_[m]= MFMA(ax[m], bn, in_[m]);
                hr[m] = MFMA(ah[m], cr, hr[m]);
                hz[m] = MFMA(ah[m], cz, hz[m]);
                hn[m] = MFMA(ah[m], cn, hn[m]);
            }
        }
        const float bir_ = Bih[n], biz_ = Bih[n+256], bin_ = Bih[n+512];
        const float bhr_ = Bhh[n], bhz_ = Bhh[n+256], bhn_ = Bhh[n+512];
        #pragma unroll
        for (int m = 0; m < 4; ++m) {
            #pragma unroll
            for (int r = 0; r < 4; ++r) {
                const int row = m*16 + quad*4 + r;
                const float hprev = bf2f(lB[swz(row, n)]);
                const float rr = sigm(ir[m][r] + bir_ + hr[m][r] + bhr_);
                const float zz = sigm(iz[m][r] + biz_ + hz[m][r] + bhz_);
                const float nn = tanh_fast(in_[m][r] + bin_ + rr*(hn[m][r] + bhn_));
                outH[(rowBase + row)*HIDD + n] = (1.0f - zz)*nn + zz*hprev;
            }
        }
    }
    __syncthreads();              // all lA(x)/lB reads complete

    // ---- P3: restage h_new (fp32, L2-hot) -> lA as bf16 ----
    #pragma unroll
    for (int i = 0; i < 8; ++i) {
        const int job  = i*256 + tid;
        const int frag = job & 31;
        const int row  = job >> 5;
        const float* src = outH + (rowBase + row)*256 + frag*8;
        float4 v0 = *(const float4*)(const void*)(src);
        float4 v1 = *(const float4*)(const void*)(src + 4);
        uint4 pk;
        pk.x = ((unsigned int)f2bf(v0.y) << 16) | f2bf(v0.x);
        pk.y = ((unsigned int)f2bf(v0.w) << 16) | f2bf(v0.z);
        pk.z = ((unsigned int)f2bf(v1.y) << 16) | f2bf(v1.x);
        pk.w = ((unsigned int)f2bf(v1.w) << 16) | f2bf(v1.z);
        *(uint4*)(void*)(lA + swzf(row, frag)) = pk;
    }
    __syncthreads();

    // ---- P4: q,k,v,g -> global bf16 ----
    for (int job = wv; job < 13; job += 4) {
        const unsigned short* W; const float* Bi; unsigned short* dst; int nb;
        if      (job < 4)  { W = Wq; Bi = Bq; dst = wsQ; nb = job;     }
        else if (job < 8)  { W = Wk; Bi = Bk; dst = wsK; nb = job - 4; }
        else if (job < 12) { W = Wv; Bi = Bv; dst = wsV; nb = job - 8; }
        else               { W = Wg; Bi = Bg; dst = wsG; nb = 0;       }
        const bool isg   = (job == 12);
        const bool valid = !isg || (l15 < 4);
        const int n = nb*16 + l15;
        f32x4 ac[4];
        #pragma unroll
        for (int m = 0; m < 4; ++m) ac[m] = (f32x4){0.f,0.f,0.f,0.f};
        #pragma unroll
        for (int kt = 0; kt < 8; ++kt) {
            const int frag = kt*4 + quad;
            bf16x8 bw = valid ? ldfrag(W + n*HIDD + frag*8) : zfrag();
            #pragma unroll
            for (int m = 0; m < 4; ++m)
                ac[m] = MFMA(ldfrag(lA + swzf(m*16 + l15, frag)), bw, ac[m]);
        }
        if (valid) {
            const float b = Bi[n];
            #pragma unroll
            for (int m = 0; m < 4; ++m) {
                #pragma unroll
                for (int r = 0; r < 4; ++r) {
                    const int row = m*16 + quad*4 + r;
                    const float v = ac[m][r] + b;
                    if (isg) dst[(rowBase + row)*4  + l15]          = f2bf(v);
                    else     dst[(rowBase + row)*64 + nb*16 + l15]  = f2bf(v);
                }
            }
        }
    }
}

// =====================================================================
// K23: fused attention + policy head. 64 rows (=2 batches)/block,
// 256 threads. q/k/v staged into the p1x LDS buffer (overlay), msg in
// LDS only. No cross-barrier register carry -> ~70 regs, no spills.
// LDS = 32 + 32 + 8 + 0.5 KB -> 2 blocks/CU.
// =====================================================================
#define QS 68   // padded LDS row stride for q/k/v staging
__global__ void __launch_bounds__(256, 2)
k23_attn_policy(const float* __restrict__ gHnew,
                const unsigned short* __restrict__ wsW,
                const unsigned short* __restrict__ wsQ,
                const unsigned short* __restrict__ wsK,
                const unsigned short* __restrict__ wsV,
                const unsigned short* __restrict__ wsG,
                const float* __restrict__ Bp1, const float* __restrict__ Bp2,
                float* __restrict__ outL)
{
    __shared__ __align__(16) unsigned short lH[MT*256];   // h (bf16 swz)
    __shared__ __align__(16) unsigned short lP[MT*256];   // qkv staging -> p1x
    __shared__ __align__(16) unsigned short lM[MT*64];    // msg (swz64)
    __shared__ __align__(16) unsigned short sG[2*32*4];   // gate logits

    const unsigned short* Wp1 = wsW + WO_WP1;
    const unsigned short* Wp2 = wsW + WO_WP2;

    const int tid  = (int)threadIdx.x;
    const int lane = tid & 63;
    const int wv   = tid >> 6;
    const int l15  = lane & 15;
    const int quad = lane >> 4;
    const long rowBase = (long)blockIdx.x * MT;
    const long b0 = (long)blockIdx.x * 2;

    // ---- A: stage h (fp32->bf16 swz into lH), q/k/v -> lP overlay, g -> sG ----
    #pragma unroll
    for (int i = 0; i < 8; ++i) {
        const int job  = i*256 + tid;
        const int frag = job & 31;
        const int row  = job >> 5;
        const float* src = gHnew + (rowBase + row)*256 + frag*8;
        float4 v0 = *(const float4*)(const void*)(src);
        float4 v1 = *(const float4*)(const void*)(src + 4);
        uint4 pk;
        pk.x = ((unsigned int)f2bf(v0.y) << 16) | f2bf(v0.x);
        pk.y = ((unsigned int)f2bf(v0.w) << 16) | f2bf(v0.z);
        pk.z = ((unsigned int)f2bf(v1.y) << 16) | f2bf(v1.x);
        pk.w = ((unsigned int)f2bf(v1.w) << 16) | f2bf(v1.z);
        *(uint4*)(void*)(lH + swzf(row, frag)) = pk;
    }
    // q/k/v: [b][mat][32][QS] inside lP. 3072 ushort4 jobs.
    #pragma unroll
    for (int i = 0; i < 12; ++i) {
        const int j  = i*256 + tid;
        const int b  = (j >= 1536) ? 1 : 0;
        const int jj = b ? (j - 1536) : j;
        const int mat = jj >> 9;
        const int e   = jj & 511;
        const int row = e >> 4, c4 = e & 15;
        const unsigned short* srcm = (mat == 0) ? wsQ : (mat == 1) ? wsK : wsV;
        *(ushort4*)(void*)(lP + ((b*3 + mat)*32 + row)*QS + c4*4) =
            *(const ushort4*)(const void*)(srcm + ((b0 + b)*32 + row)*64 + c4*4);
    }
    if (tid < 64) {
        const int b = tid >> 5, row = tid & 31;
        *(ushort4*)(void*)(sG + (b*32 + row)*4) =
            *(const ushort4*)(const void*)(wsG + ((b0 + b)*32 + row)*4);
    }
    __syncthreads();

    // ---- B: sparse attention, 1 thread per (b,h,qi); msg -> lM ----
    {
        const int b  = tid >> 7;
        const int h  = (tid >> 5) & 3;
        const int qi = tid & 31;
        const unsigned short* q_ = lP + (b*3 + 0)*32*QS;
        const unsigned short* k_ = lP + (b*3 + 1)*32*QS;
        const unsigned short* v_ = lP + (b*3 + 2)*32*QS;

        float qv[16];
        #pragma unroll
        for (int c = 0; c < 16; ++c) qv[c] = bf2f(q_[qi*QS + h*16 + c]);
        float s0[32];
        #pragma unroll
        for (int ki = 0; ki < 32; ++ki) {
            float acc = 0.0f;
            #pragma unroll
            for (int c = 0; c < 16; ++c) acc += qv[c] * bf2f(k_[ki*QS + h*16 + c]);
            acc *= 0.25f;                        // 1/sqrt(16)
            s0[ki] = (ki == qi) ? NEGV : acc;    // diagonal mask
        }
        // top-8, lowest index wins ties (matches lax.top_k)
        unsigned int mask = 0u;
        float m1 = 0.0f;
        for (int t = 0; t < 8; ++t) {
            float best = -3.0e38f; int bidx = 0;
            #pragma unroll
            for (int i = 0; i < 32; ++i) {
                bool better = (((mask >> i) & 1u) == 0u) && (s0[i] > best);
                best = better ? s0[i] : best;
                bidx = better ? i : bidx;
            }
            mask |= (1u << bidx);
            if (t == 0) m1 = best;
        }
        float sum = 0.0f;
        #pragma unroll
        for (int i = 0; i < 32; ++i) {
            const float e = ((mask >> i) & 1u) ? __expf(s0[i] - m1) : 0.0f;
            s0[i] = e;
            sum += e;
        }
        const float inv = frcp(sum);
        const float gate = sigm(bf2f(sG[(b*32 + qi)*4 + h]));
        float msg[16];
        #pragma unroll
        for (int c = 0; c < 16; ++c) msg[c] = 0.0f;
        #pragma unroll
        for (int ki = 0; ki < 32; ++ki) {
            const float al = s0[ki] * inv;
            #pragma unroll
            for (int c = 0; c < 16; ++c) msg[c] += al * bf2f(v_[ki*QS + h*16 + c]);
        }
        const int mrow = b*32 + qi;
        #pragma unroll
        for (int c = 0; c < 16; ++c)
            lM[swz64(mrow, h*16 + c)] = f2bf(msg[c] * gate);
    }
    __syncthreads();   // all q/k/v reads done; msg complete; lP reusable

    // ---- C: p1x = relu([h | msg] @ Wp1^T + b) -> lP (bf16 swz) ----
    #pragma unroll
    for (int i4 = 0; i4 < 4; ++i4) {
        const int nt = i4*4 + wv;
        const int n  = nt*16 + l15;
        f32x4 a0 = {0.f,0.f,0.f,0.f}, a1 = {0.f,0.f,0.f,0.f};
        f32x4 a2 = {0.f,0.f,0.f,0.f}, a3 = {0.f,0.f,0.f,0.f};
        #pragma unroll
        for (int kt = 0; kt < 10; ++kt) {
            bf16x8 bw = ldfrag(Wp1 + n*PIN + kt*32 + quad*8);
            bf16x8 f0, f1, f2, f3;
            if (kt < 8) {
                const int frag = kt*4 + quad;
                f0 = ldfrag(lH + swzf(     l15, frag));
                f1 = ldfrag(lH + swzf(16 + l15, frag));
                f2 = ldfrag(lH + swzf(32 + l15, frag));
                f3 = ldfrag(lH + swzf(48 + l15, frag));
            } else {
                const int frag = (kt - 8)*4 + quad;
                f0 = ldfrag(lM + swzf64(     l15, frag));
                f1 = ldfrag(lM + swzf64(16 + l15, frag));
                f2 = ldfrag(lM + swzf64(32 + l15, frag));
                f3 = ldfrag(lM + swzf64(48 + l15, frag));
            }
            a0 = MFMA(f0, bw, a0); a1 = MFMA(f1, bw, a1);
            a2 = MFMA(f2, bw, a2); a3 = MFMA(f3, bw, a3);
        }
        const float b = Bp1[n];
        #pragma unroll
        for (int r = 0; r < 4; ++r) {
            lP[swz(     quad*4 + r, n)] = f2bf(fmaxf(a0[r] + b, 0.f));
            lP[swz(16 + quad*4 + r, n)] = f2bf(fmaxf(a1[r] + b, 0.f));
            lP[swz(32 + quad*4 + r, n)] = f2bf(fmaxf(a2[r] + b, 0.f));
            lP[swz(48 + quad*4 + r, n)] = f2bf(fmaxf(a3[r] + b, 0.f));
        }
    }
    __syncthreads();

    // ---- D: logits = p1x @ Wp2^T + b ----
    for (int j = wv; j < 8; j += 4) {
        const int ntile = j >> 2, m = j & 3;
        const int n = ntile*16 + l15;
        const bool valid = (n < NACTN);
        f32x4 ac = {0.f,0.f,0.f,0.f};
        #pragma unroll
        for (int kt = 0; kt < 8; ++kt) {
            const int frag = kt*4 + quad;
            bf16x8 bw = valid ? ldfrag(Wp2 + n*HIDD + frag*8) : zfrag();
            ac = MFMA(ldfrag(lP + swzf(m*16 + l15, frag)), bw, ac);
        }
        if (valid) {
            const float b = Bp2[n];
            #pragma unroll
            for (int r = 0; r < 4; ++r)
                outL[(rowBase + m*16 + quad*4 + r)*NACTN + n] = ac[r] + b;
        }
    }
}

extern "C" void kernel_launch(void* const* d_in, const int* in_sizes, int n_in,
                              void* d_out, int out_size, void* d_ws, size_t ws_size,
                              hipStream_t stream) {
    (void)in_sizes; (void)n_in; (void)ws_size; (void)out_size;
    const float* gIn = (const float*)d_in[0];
    const float* gH  = (const float*)d_in[1];
    const float* W1  = (const float*)d_in[2];
    const float* B1  = (const float*)d_in[3];
    const float* Wih = (const float*)d_in[4];
    const float* Whh = (const float*)d_in[5];
    const float* Bih = (const float*)d_in[6];
    const float* Bhh = (const float*)d_in[7];
    const float* Wq  = (const float*)d_in[8];
    const float* Bq  = (const float*)d_in[9];
    const float* Wk  = (const float*)d_in[10];
    const float* Bk  = (const float*)d_in[11];
    const float* Wv  = (const float*)d_in[12];
    const float* Bv  = (const float*)d_in[13];
    const float* Wg  = (const float*)d_in[14];
    const float* Bg  = (const float*)d_in[15];
    const float* Wp1 = (const float*)d_in[16];
    const float* Bp1 = (const float*)d_in[17];
    const float* Wp2 = (const float*)d_in[18];
    const float* Bp2 = (const float*)d_in[19];
    float* outL = (float*)d_out;
    float* outH = outL + (size_t)NBATCH * NAG * NACTN;
    unsigned short* wsW = (unsigned short*)d_ws;

    hipLaunchKernelGGL(convert_weights, dim3(582), dim3(256), 0, stream,
        W1, Wih, Whh, Wq, Wk, Wv, Wg, Wp1, Wp2, wsW);
    hipLaunchKernelGGL(k1_gru_qkvg, dim3(NROWS/MT), dim3(256), 0, stream,
        gIn, gH, wsW, B1, Bih, Bhh, Bq, Bk, Bv, Bg,
        outH, wsW + WSO_Q, wsW + WSO_K, wsW + WSO_V, wsW + WSO_G);
    hipLaunchKernelGGL(k23_attn_policy, dim3(NROWS/MT), dim3(256), 0, stream,
        outH, wsW, wsW + WSO_Q, wsW + WSO_K, wsW + WSO_V, wsW + WSO_G,
        Bp1, Bp2, outL);
}

// Round 6
// 388.917 us; speedup vs baseline: 3.0227x; 1.0241x over previous
//
#include <hip/hip_runtime.h>
#include <hip/hip_bf16.h>
#include <math.h>

#define NBATCH 2048
#define NAG 32
#define HIDD 256
#define INDIM 256
#define PIN 320
#define NACTN 20
#define NEGV -1e10f
#define MT 64                      // rows per block (= 2 batches)
#define NROWS (NBATCH*NAG)         // 65536

typedef __attribute__((ext_vector_type(8))) __bf16 bf16x8;
typedef __attribute__((ext_vector_type(4))) float f32x4;

// ---- bf16 weight cache layout in d_ws (element offsets) ----
#define WO_W1   0
#define WO_WIH  65536
#define WO_WHH  262144
#define WO_WQ   458752
#define WO_WK   475136
#define WO_WV   491520
#define WO_WG   507904
#define WO_WP1  508928
#define WO_WP2  590848

__device__ __forceinline__ unsigned short f2bf(float f) {
    union { float f; unsigned int i; } x; x.f = f;
    unsigned int r = x.i + 0x7fffu + ((x.i >> 16) & 1u);
    return (unsigned short)(r >> 16);
}
__device__ __forceinline__ float bf2f(unsigned short u) {
    union { unsigned int i; float f; } x; x.i = ((unsigned int)u) << 16; return x.f;
}
__device__ __forceinline__ float frcp(float x) { return __builtin_amdgcn_rcpf(x); }
__device__ __forceinline__ float sigm(float x) { return frcp(1.0f + __expf(-x)); }
__device__ __forceinline__ float tanh_fast(float x) {
    float e = __expf(2.0f * x);
    return 1.0f - 2.0f * frcp(e + 1.0f);
}

// swizzled addressing for 256-col bf16 buffers
__device__ __forceinline__ int swz(int row, int col) {
    return row*256 + ((((col >> 3)) ^ (row & 7)) << 3) + (col & 7);
}
__device__ __forceinline__ int swzf(int row, int frag) {   // 8-elem fragment base
    return row*256 + ((frag ^ (row & 7)) << 3);
}
// swizzled addressing for 64-col bf16 msg buffer
__device__ __forceinline__ int swz64(int row, int col) {
    return row*64 + ((((col >> 3)) ^ (row & 7)) << 3) + (col & 7);
}
__device__ __forceinline__ int swzf64(int row, int frag) {
    return row*64 + ((frag ^ (row & 7)) << 3);
}

__device__ __forceinline__ bf16x8 ldfrag(const unsigned short* p) {
    return *(const bf16x8*)(const void*)p;
}
union ZU { uint4 u; bf16x8 v; };
__device__ __forceinline__ bf16x8 zfrag() {
    ZU x; x.u = make_uint4(0u, 0u, 0u, 0u); return x.v;
}
#define MFMA(a,b,c) __builtin_amdgcn_mfma_f32_16x16x32_bf16(a,b,c,0,0,0)

// ---- pre-pass: convert fp32 weight matrices to bf16 in d_ws ----
__global__ void __launch_bounds__(256)
convert_weights(const float* __restrict__ W1,  const float* __restrict__ Wih,
                const float* __restrict__ Whh, const float* __restrict__ Wq,
                const float* __restrict__ Wk,  const float* __restrict__ Wv,
                const float* __restrict__ Wg,  const float* __restrict__ Wp1,
                const float* __restrict__ Wp2, unsigned short* __restrict__ dst)
{
    int b = (int)blockIdx.x;
    const float* src; int base;
    if      (b <  64) { src = W1;  base = WO_W1;              }
    else if (b < 256) { src = Wih; base = WO_WIH; b -=  64;   }
    else if (b < 448) { src = Whh; base = WO_WHH; b -= 256;   }
    else if (b < 464) { src = Wq;  base = WO_WQ;  b -= 448;   }
    else if (b < 480) { src = Wk;  base = WO_WK;  b -= 464;   }
    else if (b < 496) { src = Wv;  base = WO_WV;  b -= 480;   }
    else if (b < 497) { src = Wg;  base = WO_WG;  b -= 496;   }
    else if (b < 577) { src = Wp1; base = WO_WP1; b -= 497;   }
    else              { src = Wp2; base = WO_WP2; b -= 577;   }
    const int idx = b * 1024 + (int)threadIdx.x * 4;
    float4 v = *(const float4*)(const void*)(src + idx);
    ushort4 u;
    u.x = f2bf(v.x); u.y = f2bf(v.y); u.z = f2bf(v.z); u.w = f2bf(v.w);
    *(ushort4*)(void*)(dst + base + idx) = u;
}

// =====================================================================
// Megakernel: one block = 64 rows = 2 batches. Full forward pass.
// LDS lifecycle:  lA: IN -> x -> h       lB: h_old -> q/k/v -> p1x
//                 lM: msg                sG: gate logits
// 72.5 KB LDS -> 2 blocks/CU, (256,2) -> 128 VGPR budget (P2-proven).
// =====================================================================
#define QS 68   // padded LDS row stride for q/k/v staging
__global__ void __launch_bounds__(256, 2)
mega(const float* __restrict__ gIn, const float* __restrict__ gH,
     const unsigned short* __restrict__ wsW,
     const float* __restrict__ B1,
     const float* __restrict__ Bih, const float* __restrict__ Bhh,
     const float* __restrict__ Bq,  const float* __restrict__ Bk,
     const float* __restrict__ Bv,  const float* __restrict__ Bg,
     const float* __restrict__ Bp1, const float* __restrict__ Bp2,
     float* __restrict__ outH, float* __restrict__ outL)
{
    __shared__ __align__(16) unsigned short lA[MT*256];   // IN -> x -> h
    __shared__ __align__(16) unsigned short lB[MT*256];   // h_old -> qkv -> p1x
    __shared__ __align__(16) unsigned short lM[MT*64];    // msg (swz64)
    __shared__ __align__(16) unsigned short sG[2*32*4];   // gate logits

    const unsigned short* W1  = wsW + WO_W1;
    const unsigned short* Wih = wsW + WO_WIH;
    const unsigned short* Whh = wsW + WO_WHH;
    const unsigned short* Wq  = wsW + WO_WQ;
    const unsigned short* Wk  = wsW + WO_WK;
    const unsigned short* Wv  = wsW + WO_WV;
    const unsigned short* Wg  = wsW + WO_WG;
    const unsigned short* Wp1 = wsW + WO_WP1;
    const unsigned short* Wp2 = wsW + WO_WP2;

    const int tid  = (int)threadIdx.x;
    const int lane = tid & 63;
    const int wv   = tid >> 6;
    const int l15  = lane & 15;
    const int quad = lane >> 4;
    const long rowBase = (long)blockIdx.x * MT;

    // ---- P0: stage IN -> lA, h_old -> lB (fp32 -> bf16, swizzled) ----
    #pragma unroll
    for (int i = 0; i < 16; ++i) {
        const int job  = i*256 + tid;        // 4096 = 2 bufs x 64 rows x 32 frags
        const int frag = job & 31;
        const int row  = (job >> 5) & 63;
        const int buf  = job >> 11;
        const float* src = (buf ? gH : gIn) + (rowBase + row)*256 + frag*8;
        float4 v0 = *(const float4*)(const void*)(src);
        float4 v1 = *(const float4*)(const void*)(src + 4);
        uint4 pk;
        pk.x = ((unsigned int)f2bf(v0.y) << 16) | f2bf(v0.x);
        pk.y = ((unsigned int)f2bf(v0.w) << 16) | f2bf(v0.z);
        pk.z = ((unsigned int)f2bf(v1.y) << 16) | f2bf(v1.x);
        pk.w = ((unsigned int)f2bf(v1.w) << 16) | f2bf(v1.z);
        unsigned short* dst = buf ? lB : lA;
        *(uint4*)(void*)(dst + swzf(row, frag)) = pk;
    }
    __syncthreads();

    // ---- P1: x = relu(IN @ W1^T + b1) -> regs, then overlay onto lA ----
    f32x4 xa[4][4];
    #pragma unroll
    for (int i4 = 0; i4 < 4; ++i4) {
        const int nt = i4*4 + wv;
        const int n  = nt*16 + l15;
        f32x4 a0 = {0.f,0.f,0.f,0.f}, a1 = {0.f,0.f,0.f,0.f};
        f32x4 a2 = {0.f,0.f,0.f,0.f}, a3 = {0.f,0.f,0.f,0.f};
        #pragma unroll
        for (int kt = 0; kt < 8; ++kt) {
            const int frag = kt*4 + quad;
            bf16x8 bw = ldfrag(W1 + n*INDIM + frag*8);
            a0 = MFMA(ldfrag(lA + swzf(     l15, frag)), bw, a0);
            a1 = MFMA(ldfrag(lA + swzf(16 + l15, frag)), bw, a1);
            a2 = MFMA(ldfrag(lA + swzf(32 + l15, frag)), bw, a2);
            a3 = MFMA(ldfrag(lA + swzf(48 + l15, frag)), bw, a3);
        }
        const float b = B1[n];
        #pragma unroll
        for (int r = 0; r < 4; ++r) {
            a0[r] = fmaxf(a0[r] + b, 0.f); a1[r] = fmaxf(a1[r] + b, 0.f);
            a2[r] = fmaxf(a2[r] + b, 0.f); a3[r] = fmaxf(a3[r] + b, 0.f);
        }
        xa[i4][0] = a0; xa[i4][1] = a1; xa[i4][2] = a2; xa[i4][3] = a3;
    }
    __syncthreads();              // all IN reads complete
    #pragma unroll
    for (int i4 = 0; i4 < 4; ++i4) {
        const int nt = i4*4 + wv;
        #pragma unroll
        for (int m = 0; m < 4; ++m) {
            #pragma unroll
            for (int r = 0; r < 4; ++r)
                lA[swz(m*16 + quad*4 + r, nt*16 + l15)] = f2bf(xa[i4][m][r]);
        }
    }
    __syncthreads();

    // ---- P2: GRU -> h_new (fp32 to outH) ----
    for (int jt = wv; jt < 16; jt += 4) {
        const int n = jt*16 + l15;
        f32x4 ir[4], iz[4], in_[4], hr[4], hz[4], hn[4];
        #pragma unroll
        for (int m = 0; m < 4; ++m) {
            ir[m] = (f32x4){0.f,0.f,0.f,0.f}; iz[m] = (f32x4){0.f,0.f,0.f,0.f};
            in_[m]= (f32x4){0.f,0.f,0.f,0.f}; hr[m] = (f32x4){0.f,0.f,0.f,0.f};
            hz[m] = (f32x4){0.f,0.f,0.f,0.f}; hn[m] = (f32x4){0.f,0.f,0.f,0.f};
        }
        #pragma unroll 2
        for (int kt = 0; kt < 8; ++kt) {
            const int frag = kt*4 + quad;
            const int k0 = frag*8;
            bf16x8 ax[4], ah[4];
            #pragma unroll
            for (int m = 0; m < 4; ++m) {
                ax[m] = ldfrag(lA + swzf(m*16 + l15, frag));
                ah[m] = ldfrag(lB + swzf(m*16 + l15, frag));
            }
            bf16x8 br = ldfrag(Wih + (n      )*HIDD + k0);
            bf16x8 bz = ldfrag(Wih + (n + 256)*HIDD + k0);
            bf16x8 bn = ldfrag(Wih + (n + 512)*HIDD + k0);
            bf16x8 cr = ldfrag(Whh + (n      )*HIDD + k0);
            bf16x8 cz = ldfrag(Whh + (n + 256)*HIDD + k0);
            bf16x8 cn = ldfrag(Whh + (n + 512)*HIDD + k0);
            #pragma unroll
            for (int m = 0; m < 4; ++m) {
                ir[m] = MFMA(ax[m], br, ir[m]);
                iz[m] = MFMA(ax[m], bz, iz[m]);
                in_[m]= MFMA(ax[m], bn, in_[m]);
                hr[m] = MFMA(ah[m], cr, hr[m]);
                hz[m] = MFMA(ah[m], cz, hz[m]);
                hn[m] = MFMA(ah[m], cn, hn[m]);
            }
        }
        const float bir_ = Bih[n], biz_ = Bih[n+256], bin_ = Bih[n+512];
        const float bhr_ = Bhh[n], bhz_ = Bhh[n+256], bhn_ = Bhh[n+512];
        #pragma unroll
        for (int m = 0; m < 4; ++m) {
            #pragma unroll
            for (int r = 0; r < 4; ++r) {
                const int row = m*16 + quad*4 + r;
                const float hprev = bf2f(lB[swz(row, n)]);
                const float rr = sigm(ir[m][r] + bir_ + hr[m][r] + bhr_);
                const float zz = sigm(iz[m][r] + biz_ + hz[m][r] + bhz_);
                const float nn = tanh_fast(in_[m][r] + bin_ + rr*(hn[m][r] + bhn_));
                outH[(rowBase + row)*HIDD + n] = (1.0f - zz)*nn + zz*hprev;
            }
        }
    }
    __syncthreads();              // all lA(x)/lB(h_old) reads complete

    // ---- P3: restage h_new (fp32, L2-hot) -> lA as bf16 ----
    #pragma unroll
    for (int i = 0; i < 8; ++i) {
        const int job  = i*256 + tid;
        const int frag = job & 31;
        const int row  = job >> 5;
        const float* src = outH + (rowBase + row)*256 + frag*8;
        float4 v0 = *(const float4*)(const void*)(src);
        float4 v1 = *(const float4*)(const void*)(src + 4);
        uint4 pk;
        pk.x = ((unsigned int)f2bf(v0.y) << 16) | f2bf(v0.x);
        pk.y = ((unsigned int)f2bf(v0.w) << 16) | f2bf(v0.z);
        pk.z = ((unsigned int)f2bf(v1.y) << 16) | f2bf(v1.x);
        pk.w = ((unsigned int)f2bf(v1.w) << 16) | f2bf(v1.z);
        *(uint4*)(void*)(lA + swzf(row, frag)) = pk;
    }
    __syncthreads();

    // ---- P4: q,k,v -> lB ([b][mat][32][QS]), g -> sG ----
    for (int job = wv; job < 13; job += 4) {
        const unsigned short* W; const float* Bi; int mat, nb;
        if      (job < 4)  { W = Wq; Bi = Bq; mat = 0; nb = job;     }
        else if (job < 8)  { W = Wk; Bi = Bk; mat = 1; nb = job - 4; }
        else if (job < 12) { W = Wv; Bi = Bv; mat = 2; nb = job - 8; }
        else               { W = Wg; Bi = Bg; mat = 3; nb = 0;       }
        const bool isg   = (job == 12);
        const bool valid = !isg || (l15 < 4);
        const int n = nb*16 + l15;
        f32x4 ac[4];
        #pragma unroll
        for (int m = 0; m < 4; ++m) ac[m] = (f32x4){0.f,0.f,0.f,0.f};
        #pragma unroll
        for (int kt = 0; kt < 8; ++kt) {
            const int frag = kt*4 + quad;
            bf16x8 bw = valid ? ldfrag(W + n*HIDD + frag*8) : zfrag();
            #pragma unroll
            for (int m = 0; m < 4; ++m)
                ac[m] = MFMA(ldfrag(lA + swzf(m*16 + l15, frag)), bw, ac[m]);
        }
        if (valid) {
            const float b = Bi[n];
            #pragma unroll
            for (int m = 0; m < 4; ++m) {
                #pragma unroll
                for (int r = 0; r < 4; ++r) {
                    const int row = m*16 + quad*4 + r;     // 0..63
                    const int bb  = row >> 5, qi = row & 31;
                    const float v = ac[m][r] + b;
                    if (isg) sG[bb*128 + qi*4 + l15] = f2bf(v);
                    else     lB[((bb*3 + mat)*32 + qi)*QS + nb*16 + l15] = f2bf(v);
                }
            }
        }
    }
    __syncthreads();

    // ---- P5: sparse attention, 1 thread per (b,h,qi); msg -> lM ----
    {
        const int b  = tid >> 7;
        const int h  = (tid >> 5) & 3;
        const int qi = tid & 31;
        const unsigned short* q_ = lB + (b*3 + 0)*32*QS;
        const unsigned short* k_ = lB + (b*3 + 1)*32*QS;
        const unsigned short* v_ = lB + (b*3 + 2)*32*QS;

        float qv[16];
        #pragma unroll
        for (int c = 0; c < 16; ++c) qv[c] = bf2f(q_[qi*QS + h*16 + c]);
        float s0[32];
        #pragma unroll
        for (int ki = 0; ki < 32; ++ki) {
            float acc = 0.0f;
            #pragma unroll
            for (int c = 0; c < 16; ++c) acc += qv[c] * bf2f(k_[ki*QS + h*16 + c]);
            acc *= 0.25f;                        // 1/sqrt(16)
            s0[ki] = (ki == qi) ? NEGV : acc;    // diagonal mask
        }
        // top-8, lowest index wins ties (matches lax.top_k)
        unsigned int mask = 0u;
        float m1 = 0.0f;
        for (int t = 0; t < 8; ++t) {
            float best = -3.0e38f; int bidx = 0;
            #pragma unroll
            for (int i = 0; i < 32; ++i) {
                bool better = (((mask >> i) & 1u) == 0u) && (s0[i] > best);
                best = better ? s0[i] : best;
                bidx = better ? i : bidx;
            }
            mask |= (1u << bidx);
            if (t == 0) m1 = best;
        }
        float sum = 0.0f;
        #pragma unroll
        for (int i = 0; i < 32; ++i) {
            const float e = ((mask >> i) & 1u) ? __expf(s0[i] - m1) : 0.0f;
            s0[i] = e;
            sum += e;
        }
        const float inv = frcp(sum);
        const float gate = sigm(bf2f(sG[b*128 + qi*4 + h]));
        float msg[16];
        #pragma unroll
        for (int c = 0; c < 16; ++c) msg[c] = 0.0f;
        #pragma unroll
        for (int ki = 0; ki < 32; ++ki) {
            const float al = s0[ki] * inv;
            #pragma unroll
            for (int c = 0; c < 16; ++c) msg[c] += al * bf2f(v_[ki*QS + h*16 + c]);
        }
        const int mrow = b*32 + qi;
        #pragma unroll
        for (int c = 0; c < 16; ++c)
            lM[swz64(mrow, h*16 + c)] = f2bf(msg[c] * gate);
    }
    __syncthreads();   // q/k/v reads done; msg complete; lB reusable

    // ---- P6: p1x = relu([h | msg] @ Wp1^T + b) -> lB (bf16 swz) ----
    #pragma unroll
    for (int i4 = 0; i4 < 4; ++i4) {
        const int nt = i4*4 + wv;
        const int n  = nt*16 + l15;
        f32x4 a0 = {0.f,0.f,0.f,0.f}, a1 = {0.f,0.f,0.f,0.f};
        f32x4 a2 = {0.f,0.f,0.f,0.f}, a3 = {0.f,0.f,0.f,0.f};
        #pragma unroll
        for (int kt = 0; kt < 10; ++kt) {
            bf16x8 bw = ldfrag(Wp1 + n*PIN + kt*32 + quad*8);
            bf16x8 f0, f1, f2, f3;
            if (kt < 8) {
                const int frag = kt*4 + quad;
                f0 = ldfrag(lA + swzf(     l15, frag));
                f1 = ldfrag(lA + swzf(16 + l15, frag));
                f2 = ldfrag(lA + swzf(32 + l15, frag));
                f3 = ldfrag(lA + swzf(48 + l15, frag));
            } else {
                const int frag = (kt - 8)*4 + quad;
                f0 = ldfrag(lM + swzf64(     l15, frag));
                f1 = ldfrag(lM + swzf64(16 + l15, frag));
                f2 = ldfrag(lM + swzf64(32 + l15, frag));
                f3 = ldfrag(lM + swzf64(48 + l15, frag));
            }
            a0 = MFMA(f0, bw, a0); a1 = MFMA(f1, bw, a1);
            a2 = MFMA(f2, bw, a2); a3 = MFMA(f3, bw, a3);
        }
        const float b = Bp1[n];
        #pragma unroll
        for (int r = 0; r < 4; ++r) {
            lB[swz(     quad*4 + r, n)] = f2bf(fmaxf(a0[r] + b, 0.f));
            lB[swz(16 + quad*4 + r, n)] = f2bf(fmaxf(a1[r] + b, 0.f));
            lB[swz(32 + quad*4 + r, n)] = f2bf(fmaxf(a2[r] + b, 0.f));
            lB[swz(48 + quad*4 + r, n)] = f2bf(fmaxf(a3[r] + b, 0.f));
        }
    }
    __syncthreads();

    // ---- P7: logits = p1x @ Wp2^T + b ----
    for (int j = wv; j < 8; j += 4) {
        const int ntile = j >> 2, m = j & 3;
        const int n = ntile*16 + l15;
        const bool valid = (n < NACTN);
        f32x4 ac = {0.f,0.f,0.f,0.f};
        #pragma unroll
        for (int kt = 0; kt < 8; ++kt) {
            const int frag = kt*4 + quad;
            bf16x8 bw = valid ? ldfrag(Wp2 + n*HIDD + frag*8) : zfrag();
            ac = MFMA(ldfrag(lB + swzf(m*16 + l15, frag)), bw, ac);
        }
        if (valid) {
            const float b = Bp2[n];
            #pragma unroll
            for (int r = 0; r < 4; ++r)
                outL[(rowBase + m*16 + quad*4 + r)*NACTN + n] = ac[r] + b;
        }
    }
}

extern "C" void kernel_launch(void* const* d_in, const int* in_sizes, int n_in,
                              void* d_out, int out_size, void* d_ws, size_t ws_size,
                              hipStream_t stream) {
    (void)in_sizes; (void)n_in; (void)ws_size; (void)out_size;
    const float* gIn = (const float*)d_in[0];
    const float* gH  = (const float*)d_in[1];
    const float* W1  = (const float*)d_in[2];
    const float* B1  = (const float*)d_in[3];
    const float* Wih = (const float*)d_in[4];
    const float* Whh = (const float*)d_in[5];
    const float* Bih = (const float*)d_in[6];
    const float* Bhh = (const float*)d_in[7];
    const float* Wq  = (const float*)d_in[8];
    const float* Bq  = (const float*)d_in[9];
    const float* Wk  = (const float*)d_in[10];
    const float* Bk  = (const float*)d_in[11];
    const float* Wv  = (const float*)d_in[12];
    const float* Bv  = (const float*)d_in[13];
    const float* Wg  = (const float*)d_in[14];
    const float* Bg  = (const float*)d_in[15];
    const float* Wp1 = (const float*)d_in[16];
    const float* Bp1 = (const float*)d_in[17];
    const float* Wp2 = (const float*)d_in[18];
    const float* Bp2 = (const float*)d_in[19];
    float* outL = (float*)d_out;
    float* outH = outL + (size_t)NBATCH * NAG * NACTN;
    unsigned short* wsW = (unsigned short*)d_ws;

    hipLaunchKernelGGL(convert_weights, dim3(582), dim3(256), 0, stream,
        W1, Wih, Whh, Wq, Wk, Wv, Wg, Wp1, Wp2, wsW);
    hipLaunchKernelGGL(mega, dim3(NROWS/MT), dim3(256), 0, stream,
        gIn, gH, wsW, B1, Bih, Bhh, Bq, Bk, Bv, Bg, Bp1, Bp2, outH, outL);
}